// Round 2
// baseline (2016.083 us; speedup 1.0000x reference)
//
#include <hip/hip_runtime.h>

// Tsit5 tableau
__device__ __constant__ float dA[6][5] = {
  {0.f, 0.f, 0.f, 0.f, 0.f},
  {0.161f, 0.f, 0.f, 0.f, 0.f},
  {-0.008480655492356989f, 0.335480655492357f, 0.f, 0.f, 0.f},
  {2.8971530571054935f, -6.359448489975075f, 4.3622954328695815f, 0.f, 0.f},
  {5.325864828439257f, -11.748883564062828f, 7.4955393428898365f, -0.09249506636175525f, 0.f},
  {5.86145544294642f, -12.92096931784711f, 8.159367898576159f, -0.071584973281401f, -0.028269050394068383f}
};
__device__ __constant__ float dC[6] = {0.f, 0.161f, 0.327f, 0.9f, 0.9800255409045097f, 1.0f};
__device__ __constant__ float dB[6] = {0.09646076681806523f, 0.01f, 0.4798896504144996f,
                                       1.379008574103742f, -3.290069515436081f, 2.324710524099774f};

#define NSTEPS 49
#define SI_S 68   // padded stage-input stride (t + 64 state + 3 zero pad); 272B rows keep f4 alignment

// Roles (block = 256 threads, 4 waves, 8 batch rows/block):
//   waves 0-1 (tid 0..127):  layer-2 owners — thread (j2=tid>>1, ks=tid&1): outs {2j2,2j2+1}, k-half ks
//   wave  2   (tid 128..191): layer-1 owners — thread l: outs {l, l+64}, full k=65 (padded to 68)
//   wave  3   (tid 192..255): layer-3 owners — thread (d2,ks): outs {2d2,2d2+1}, k-half ks
// Per Tsit5 stage: build SI (all threads), then 10-tick row pipeline:
//   tick t: L1 -> row t, L2 -> row t-1, L3 -> row t-2; one __syncthreads per tick.
extern "C" __global__ void __launch_bounds__(256, 1)
node_solve(const float* __restrict__ y0, const float* __restrict__ ts,
           const float* __restrict__ gw0, const float* __restrict__ gb0,
           const float* __restrict__ gw1, const float* __restrict__ gb1,
           const float* __restrict__ gw2, const float* __restrict__ gb2,
           float* __restrict__ out)
{
    __shared__ float sSI[8][SI_S];   // stage input [t, y+dt*A.k, pad]
    __shared__ float sH1[8][128];
    __shared__ float sH2[8][128];
    __shared__ float sK[6][8][64];
    __shared__ float sY[8][64];

    const int tid  = threadIdx.x;
    const int wave = tid >> 6;
    const int row0 = blockIdx.x * 8;

    // ---- init: y rows into LDS, zero SI pad columns ----
    {
        int r = tid >> 5, d0 = (tid & 31) * 2;
        float2 v = *(const float2*)(y0 + (size_t)(row0 + r) * 64 + d0);
        sY[r][d0] = v.x; sY[r][d0 + 1] = v.y;
        if (tid < 24) { int rr = tid / 3, c = 65 + tid % 3; sSI[rr][c] = 0.f; }
    }

    // ---- per-role weight load into registers (constant indices only -> VGPR arrays) ----
    float4 wA4[17], wB4[17];
    float bias0 = 0.f, bias1 = 0.f;

    if (wave < 2) {  // L2: w1 rows 2j2, 2j2+1, k in [ks*64, ks*64+64)
        int j2 = tid >> 1, ks = tid & 1;
        const float4* p0 = (const float4*)(gw1 + (size_t)(2 * j2) * 128 + ks * 64);
        const float4* p1 = (const float4*)(gw1 + (size_t)(2 * j2 + 1) * 128 + ks * 64);
        #pragma unroll
        for (int i = 0; i < 16; ++i) { wA4[i] = p0[i]; wB4[i] = p1[i]; }
        wA4[16] = make_float4(0.f, 0.f, 0.f, 0.f);
        wB4[16] = make_float4(0.f, 0.f, 0.f, 0.f);
        bias0 = gb1[2 * j2]; bias1 = gb1[2 * j2 + 1];
    } else if (wave == 2) {  // L1: w0 rows l, l+64 (stride 65, scalar loads; pad to 68)
        int l = tid - 128;
        #pragma unroll
        for (int i = 0; i < 17; ++i) {
            float a[4], b[4];
            #pragma unroll
            for (int c = 0; c < 4; ++c) {
                int k = i * 4 + c;
                a[c] = (k < 65) ? gw0[(size_t)l * 65 + k] : 0.f;
                b[c] = (k < 65) ? gw0[(size_t)(l + 64) * 65 + k] : 0.f;
            }
            wA4[i] = make_float4(a[0], a[1], a[2], a[3]);
            wB4[i] = make_float4(b[0], b[1], b[2], b[3]);
        }
        bias0 = gb0[l]; bias1 = gb0[l + 64];
    } else {  // L3: w2 rows 2d2, 2d2+1, k-half ks
        int l = tid - 192, d2 = l >> 1, ks = l & 1;
        const float4* p0 = (const float4*)(gw2 + (size_t)(2 * d2) * 128 + ks * 64);
        const float4* p1 = (const float4*)(gw2 + (size_t)(2 * d2 + 1) * 128 + ks * 64);
        #pragma unroll
        for (int i = 0; i < 16; ++i) { wA4[i] = p0[i]; wB4[i] = p1[i]; }
        wA4[16] = make_float4(0.f, 0.f, 0.f, 0.f);
        wB4[16] = make_float4(0.f, 0.f, 0.f, 0.f);
        bias0 = gb2[2 * d2]; bias1 = gb2[2 * d2 + 1];
    }

    const float t0v = ts[0];
    const float dtv = ts[1] - ts[0];

    __syncthreads();

    #pragma unroll 1
    for (int step = 0; step < NSTEPS; ++step) {
        const float tcur = t0v + (float)step * dtv;

        #pragma unroll 1
        for (int s = 0; s < 6; ++s) {
            // ---- build stage input (all 256 threads; 2 dims per thread) ----
            {
                int r = tid >> 5, d0 = (tid & 31) * 2;
                float a0 = 0.f, a1 = 0.f;
                for (int q = 0; q < s; ++q) {
                    float aq = dA[s][q];
                    a0 += aq * sK[q][r][d0];
                    a1 += aq * sK[q][r][d0 + 1];
                }
                sSI[r][1 + d0]     = sY[r][d0]     + dtv * a0;
                sSI[r][1 + d0 + 1] = sY[r][d0 + 1] + dtv * a1;
                if ((tid & 31) == 0) sSI[r][0] = tcur + dC[s] * dtv;
            }
            __syncthreads();

            // ---- 10-tick row pipeline ----
            #pragma unroll 1
            for (int tick = 0; tick < 10; ++tick) {
                if (wave == 2) {               // L1 on row=tick
                    if (tick < 8) {
                        const float4* x4 = (const float4*)sSI[tick];
                        float p0 = 0.f, p1 = 0.f, p2 = 0.f, p3 = 0.f;
                        #pragma unroll
                        for (int i = 0; i < 17; ++i) {
                            float4 xv = x4[i];
                            p0 += xv.x * wA4[i].x + xv.y * wA4[i].y;
                            p1 += xv.z * wA4[i].z + xv.w * wA4[i].w;
                            p2 += xv.x * wB4[i].x + xv.y * wB4[i].y;
                            p3 += xv.z * wB4[i].z + xv.w * wB4[i].w;
                        }
                        int l = tid - 128;
                        sH1[tick][l]      = fmaxf(p0 + p1 + bias0, 0.f);
                        sH1[tick][l + 64] = fmaxf(p2 + p3 + bias1, 0.f);
                    }
                } else if (wave < 2) {         // L2 on row=tick-1
                    if (tick >= 1 && tick < 9) {
                        int row = tick - 1;
                        int j2 = tid >> 1, ks = tid & 1;
                        const float4* x4 = (const float4*)(sH1[row] + ks * 64);
                        float p0 = 0.f, p1 = 0.f, p2 = 0.f, p3 = 0.f;
                        #pragma unroll
                        for (int i = 0; i < 16; ++i) {
                            float4 xv = x4[i];
                            p0 += xv.x * wA4[i].x + xv.y * wA4[i].y;
                            p1 += xv.z * wA4[i].z + xv.w * wA4[i].w;
                            p2 += xv.x * wB4[i].x + xv.y * wB4[i].y;
                            p3 += xv.z * wB4[i].z + xv.w * wB4[i].w;
                        }
                        float s0 = p0 + p1, s1 = p2 + p3;
                        s0 += __shfl_xor(s0, 1);
                        s1 += __shfl_xor(s1, 1);
                        float v = (ks ? s1 : s0) + (ks ? bias1 : bias0);
                        sH2[row][2 * j2 + ks] = fmaxf(v, 0.f);
                    }
                } else {                        // L3 on row=tick-2
                    if (tick >= 2) {
                        int row = tick - 2;
                        int l = tid - 192, d2 = l >> 1, ks = l & 1;
                        const float4* x4 = (const float4*)(sH2[row] + ks * 64);
                        float p0 = 0.f, p1 = 0.f, p2 = 0.f, p3 = 0.f;
                        #pragma unroll
                        for (int i = 0; i < 16; ++i) {
                            float4 xv = x4[i];
                            p0 += xv.x * wA4[i].x + xv.y * wA4[i].y;
                            p1 += xv.z * wA4[i].z + xv.w * wA4[i].w;
                            p2 += xv.x * wB4[i].x + xv.y * wB4[i].y;
                            p3 += xv.z * wB4[i].z + xv.w * wB4[i].w;
                        }
                        float s0 = p0 + p1, s1 = p2 + p3;
                        s0 += __shfl_xor(s0, 1);
                        s1 += __shfl_xor(s1, 1);
                        float v = (ks ? s1 : s0) + (ks ? bias1 : bias0);
                        sK[s][row][2 * d2 + ks] = v;
                    }
                }
                __syncthreads();
            }
        }

        // ---- y update (all threads, 2 dims each) ----
        {
            int r = tid >> 5, d0 = (tid & 31) * 2;
            float a0 = 0.f, a1 = 0.f;
            #pragma unroll
            for (int q = 0; q < 6; ++q) {
                float bq = dB[q];
                a0 += bq * sK[q][r][d0];
                a1 += bq * sK[q][r][d0 + 1];
            }
            sY[r][d0]     += dtv * a0;
            sY[r][d0 + 1] += dtv * a1;
        }
        __syncthreads();
    }

    // ---- write out (same thread wrote these sY entries) ----
    {
        int r = tid >> 5, d0 = (tid & 31) * 2;
        float2 v;
        v.x = sY[r][d0];
        v.y = sY[r][d0 + 1];
        *(float2*)(out + (size_t)(row0 + r) * 64 + d0) = v;
    }
}

extern "C" void kernel_launch(void* const* d_in, const int* in_sizes, int n_in,
                              void* d_out, int out_size, void* d_ws, size_t ws_size,
                              hipStream_t stream) {
    const float* y0 = (const float*)d_in[0];
    const float* ts = (const float*)d_in[1];
    const float* w0 = (const float*)d_in[2];
    const float* b0 = (const float*)d_in[3];
    const float* w1 = (const float*)d_in[4];
    const float* b1 = (const float*)d_in[5];
    const float* w2 = (const float*)d_in[6];
    const float* b2 = (const float*)d_in[7];
    float* out = (float*)d_out;

    node_solve<<<dim3(256), dim3(256), 0, stream>>>(y0, ts, w0, b0, w1, b1, w2, b2, out);
}

// Round 3
// 1218.854 us; speedup vs baseline: 1.6541x; 1.6541x over previous
//
#include <hip/hip_runtime.h>

// Tsit5 tableau
__device__ __constant__ float dA[6][5] = {
  {0.f, 0.f, 0.f, 0.f, 0.f},
  {0.161f, 0.f, 0.f, 0.f, 0.f},
  {-0.008480655492356989f, 0.335480655492357f, 0.f, 0.f, 0.f},
  {2.8971530571054935f, -6.359448489975075f, 4.3622954328695815f, 0.f, 0.f},
  {5.325864828439257f, -11.748883564062828f, 7.4955393428898365f, -0.09249506636175525f, 0.f},
  {5.86145544294642f, -12.92096931784711f, 8.159367898576159f, -0.071584973281401f, -0.028269050394068383f}
};
__device__ __constant__ float dC6[6] = {0.f, 0.161f, 0.327f, 0.9f, 0.9800255409045097f, 1.0f};
__device__ __constant__ float dB6[6] = {0.09646076681806523f, 0.01f, 0.4798896504144996f,
                                        1.379008574103742f, -3.290069515436081f, 2.324710524099774f};

#define NSTEPS 49
#define ROWS 4
#define SI_S 72   // [t, y0..y63, 7 zero pad] -> 18 float4 per row

// Block: 256 thr / 4 waves, owns 4 batch rows. Weights live in REGISTERS:
//   L1/L2: thread (j = wave*32 + lane>>1, half = lane&1): col j, k-half; combine via shfl_xor(1)
//   L3:    thread (d = wave*16 + lane>>2, quar = lane&3): col d, k-quarter; shfl_xor(1)+(2)
// Per Tsit5 stage: build-SI, L1, L2, L3 — one __syncthreads after each (4/stage).
// 2 blocks/CU so one block's barriers overlap the other block's compute.
extern "C" __global__ void __launch_bounds__(256, 2)
node_solve(const float* __restrict__ y0, const float* __restrict__ ts,
           const float* __restrict__ gw0, const float* __restrict__ gb0,
           const float* __restrict__ gw1, const float* __restrict__ gb1,
           const float* __restrict__ gw2, const float* __restrict__ gb2,
           float* __restrict__ out)
{
    __shared__ float sSI[ROWS][SI_S];
    __shared__ float sH1[ROWS][128];
    __shared__ float sH2[ROWS][128];
    __shared__ float sK[6][ROWS][64];
    __shared__ float sY[ROWS][64];

    const int tid  = threadIdx.x;
    const int wave = tid >> 6;
    const int lane = tid & 63;
    const int row0 = blockIdx.x * ROWS;

    const int j12 = wave * 32 + (lane >> 1);  // L1/L2 output col
    const int h12 = lane & 1;                 // k-half
    const int d3  = wave * 16 + (lane >> 2);  // L3 output col
    const int q3  = lane & 3;                 // k-quarter
    const int br  = wave;                     // build/update row
    const int bd  = lane;                     // build/update dim

    // ---- weights into registers (constant unroll indices -> VGPR arrays) ----
    float4 w1r[9], w2r[16], w3r[8];
    {
        // L1: w0 is [128][65]; k index in padded-SI space [0..71], weight 0 for k>=65
        #pragma unroll
        for (int i = 0; i < 9; ++i) {
            float v[4];
            #pragma unroll
            for (int c = 0; c < 4; ++c) {
                int k = h12 * 36 + i * 4 + c;
                v[c] = (k < 65) ? gw0[(size_t)j12 * 65 + k] : 0.f;
            }
            w1r[i] = make_float4(v[0], v[1], v[2], v[3]);
        }
        const float4* p2 = (const float4*)(gw1 + (size_t)j12 * 128 + h12 * 64);
        #pragma unroll
        for (int i = 0; i < 16; ++i) w2r[i] = p2[i];
        const float4* p3 = (const float4*)(gw2 + (size_t)d3 * 128 + q3 * 32);
        #pragma unroll
        for (int i = 0; i < 8; ++i) w3r[i] = p3[i];
    }
    const float b0r = gb0[j12];
    const float b1r = gb1[j12];
    const float b2r = gb2[d3];

    // ---- init LDS: y rows, SI pad columns (never rewritten) ----
    sY[br][bd] = y0[(size_t)(row0 + br) * 64 + bd];
    if (lane < 7) sSI[br][65 + lane] = 0.f;

    const float t0v = ts[0];
    const float dtv = ts[1] - ts[0];

    __syncthreads();

    #pragma unroll 1
    for (int step = 0; step < NSTEPS; ++step) {
        const float tb = t0v + (float)step * dtv;

        #pragma unroll 1
        for (int s = 0; s < 6; ++s) {
            // ---- build stage input: SI[r][1+d] = y + dt * sum_{q<s} A[s][q] k_q ----
            {
                float a = 0.f;
                for (int q = 0; q < s; ++q) a += dA[s][q] * sK[q][br][bd];
                sSI[br][1 + bd] = sY[br][bd] + dtv * a;
                if (bd == 0) sSI[br][0] = tb + dC6[s] * dtv;
            }
            __syncthreads();

            // ---- L1: out j12, k-half h12 over padded SI (36 k each) ----
            {
                const float4* x0 = (const float4*)(&sSI[0][h12 * 36]);
                const float4* x1 = (const float4*)(&sSI[1][h12 * 36]);
                const float4* x2 = (const float4*)(&sSI[2][h12 * 36]);
                const float4* x3 = (const float4*)(&sSI[3][h12 * 36]);
                float a0 = 0.f, a1 = 0.f, a2 = 0.f, a3 = 0.f;
                #pragma unroll
                for (int i = 0; i < 9; ++i) {
                    float4 w = w1r[i];
                    float4 v;
                    v = x0[i]; a0 += v.x * w.x + v.y * w.y + v.z * w.z + v.w * w.w;
                    v = x1[i]; a1 += v.x * w.x + v.y * w.y + v.z * w.z + v.w * w.w;
                    v = x2[i]; a2 += v.x * w.x + v.y * w.y + v.z * w.z + v.w * w.w;
                    v = x3[i]; a3 += v.x * w.x + v.y * w.y + v.z * w.z + v.w * w.w;
                }
                a0 += __shfl_xor(a0, 1);
                a1 += __shfl_xor(a1, 1);
                a2 += __shfl_xor(a2, 1);
                a3 += __shfl_xor(a3, 1);
                if (h12 == 0) {
                    sH1[0][j12] = fmaxf(a0 + b0r, 0.f);
                    sH1[1][j12] = fmaxf(a1 + b0r, 0.f);
                    sH1[2][j12] = fmaxf(a2 + b0r, 0.f);
                    sH1[3][j12] = fmaxf(a3 + b0r, 0.f);
                }
            }
            __syncthreads();

            // ---- L2: out j12, k-half h12 (64 k each) ----
            {
                const float4* x0 = (const float4*)(&sH1[0][h12 * 64]);
                const float4* x1 = (const float4*)(&sH1[1][h12 * 64]);
                const float4* x2 = (const float4*)(&sH1[2][h12 * 64]);
                const float4* x3 = (const float4*)(&sH1[3][h12 * 64]);
                float a0 = 0.f, a1 = 0.f, a2 = 0.f, a3 = 0.f;
                #pragma unroll
                for (int i = 0; i < 16; ++i) {
                    float4 w = w2r[i];
                    float4 v;
                    v = x0[i]; a0 += v.x * w.x + v.y * w.y + v.z * w.z + v.w * w.w;
                    v = x1[i]; a1 += v.x * w.x + v.y * w.y + v.z * w.z + v.w * w.w;
                    v = x2[i]; a2 += v.x * w.x + v.y * w.y + v.z * w.z + v.w * w.w;
                    v = x3[i]; a3 += v.x * w.x + v.y * w.y + v.z * w.z + v.w * w.w;
                }
                a0 += __shfl_xor(a0, 1);
                a1 += __shfl_xor(a1, 1);
                a2 += __shfl_xor(a2, 1);
                a3 += __shfl_xor(a3, 1);
                if (h12 == 0) {
                    sH2[0][j12] = fmaxf(a0 + b1r, 0.f);
                    sH2[1][j12] = fmaxf(a1 + b1r, 0.f);
                    sH2[2][j12] = fmaxf(a2 + b1r, 0.f);
                    sH2[3][j12] = fmaxf(a3 + b1r, 0.f);
                }
            }
            __syncthreads();

            // ---- L3: out d3, k-quarter q3 (32 k each) -> k_s ----
            {
                const float4* x0 = (const float4*)(&sH2[0][q3 * 32]);
                const float4* x1 = (const float4*)(&sH2[1][q3 * 32]);
                const float4* x2 = (const float4*)(&sH2[2][q3 * 32]);
                const float4* x3 = (const float4*)(&sH2[3][q3 * 32]);
                float a0 = 0.f, a1 = 0.f, a2 = 0.f, a3 = 0.f;
                #pragma unroll
                for (int i = 0; i < 8; ++i) {
                    float4 w = w3r[i];
                    float4 v;
                    v = x0[i]; a0 += v.x * w.x + v.y * w.y + v.z * w.z + v.w * w.w;
                    v = x1[i]; a1 += v.x * w.x + v.y * w.y + v.z * w.z + v.w * w.w;
                    v = x2[i]; a2 += v.x * w.x + v.y * w.y + v.z * w.z + v.w * w.w;
                    v = x3[i]; a3 += v.x * w.x + v.y * w.y + v.z * w.z + v.w * w.w;
                }
                a0 += __shfl_xor(a0, 1); a0 += __shfl_xor(a0, 2);
                a1 += __shfl_xor(a1, 1); a1 += __shfl_xor(a1, 2);
                a2 += __shfl_xor(a2, 1); a2 += __shfl_xor(a2, 2);
                a3 += __shfl_xor(a3, 1); a3 += __shfl_xor(a3, 2);
                if (q3 == 0) {
                    sK[s][0][d3] = a0 + b2r;
                    sK[s][1][d3] = a1 + b2r;
                    sK[s][2][d3] = a2 + b2r;
                    sK[s][3][d3] = a3 + b2r;
                }
            }
            __syncthreads();
        }

        // ---- y update (same-thread mapping as build; no extra barrier needed) ----
        {
            float a = 0.f;
            #pragma unroll
            for (int q = 0; q < 6; ++q) a += dB6[q] * sK[q][br][bd];
            sY[br][bd] += dtv * a;
        }
    }

    out[(size_t)(row0 + br) * 64 + bd] = sY[br][bd];
}

extern "C" void kernel_launch(void* const* d_in, const int* in_sizes, int n_in,
                              void* d_out, int out_size, void* d_ws, size_t ws_size,
                              hipStream_t stream) {
    const float* y0 = (const float*)d_in[0];
    const float* ts = (const float*)d_in[1];
    const float* w0 = (const float*)d_in[2];
    const float* b0 = (const float*)d_in[3];
    const float* w1 = (const float*)d_in[4];
    const float* b1 = (const float*)d_in[5];
    const float* w2 = (const float*)d_in[6];
    const float* b2 = (const float*)d_in[7];
    float* out = (float*)d_out;

    node_solve<<<dim3(512), dim3(256), 0, stream>>>(y0, ts, w0, b0, w1, b1, w2, b2, out);
}

// Round 4
// 367.762 us; speedup vs baseline: 5.4820x; 3.3142x over previous
//
#include <hip/hip_runtime.h>

typedef __attribute__((ext_vector_type(8))) short short8;
typedef __attribute__((ext_vector_type(4))) float f32x4;

// Tsit5 tableau
__device__ __constant__ float dA[6][5] = {
  {0.f, 0.f, 0.f, 0.f, 0.f},
  {0.161f, 0.f, 0.f, 0.f, 0.f},
  {-0.008480655492356989f, 0.335480655492357f, 0.f, 0.f, 0.f},
  {2.8971530571054935f, -6.359448489975075f, 4.3622954328695815f, 0.f, 0.f},
  {5.325864828439257f, -11.748883564062828f, 7.4955393428898365f, -0.09249506636175525f, 0.f},
  {5.86145544294642f, -12.92096931784711f, 8.159367898576159f, -0.071584973281401f, -0.028269050394068383f}
};
__device__ __constant__ float dC6[6] = {0.f, 0.161f, 0.327f, 0.9f, 0.9800255409045097f, 1.0f};
__device__ __constant__ float dB6[6] = {0.09646076681806523f, 0.01f, 0.4798896504144996f,
                                        1.379008574103742f, -3.290069515436081f, 2.324710524099774f};

#define NSTEPS 49
#define XS 136   // bf16 activation row stride: 272B -> A-frag ds_read_b128 at 8-cyc floor, 2-way max

// fp32 -> bf16 round-to-nearest-even (finite inputs)
__device__ __forceinline__ unsigned short f2bf(float f) {
    unsigned u = __builtin_bit_cast(unsigned, f);
    u += 0x7fff + ((u >> 16) & 1);
    return (unsigned short)(u >> 16);
}

// Block: 256 thr / 4 waves, M=4 batch rows. 512 blocks, 2 blocks/CU.
// MFMA 16x16x32 bf16; weights = register-resident B-frags (bf16), converted once.
// Wave w: L1/L2 output cols n in [32w, 32w+32); L3 cols [16w, 16w+16).
// A-frag: lane holds A[m=lane&15][k=(lane>>4)*8+j]; C/D: col=lane&15, row=(lane>>4)*4+reg.
// M=4 => all valid C rows live in lanes 0..15 (quad 0), row = reg.
extern "C" __global__ void __launch_bounds__(256, 2)
node_solve(const float* __restrict__ y0, const float* __restrict__ ts,
           const float* __restrict__ gw0, const float* __restrict__ gb0,
           const float* __restrict__ gw1, const float* __restrict__ gb1,
           const float* __restrict__ gw2, const float* __restrict__ gb2,
           float* __restrict__ out)
{
    __shared__ __align__(16) unsigned short sSI[16 * XS];  // [t, y', pad..] bf16, K-extent 96
    __shared__ __align__(16) unsigned short sH1[16 * XS];  // hidden1 bf16, K=128
    __shared__ __align__(16) unsigned short sH2[16 * XS];  // hidden2 bf16, K=128
    __shared__ float sK[6 * 4 * 64];                        // stage derivs fp32
    __shared__ float sY[4 * 64];                            // state fp32

    const int tid  = threadIdx.x;
    const int w    = tid >> 6;       // wave 0..3
    const int lane = tid & 63;
    const int q    = lane >> 4;      // quad
    const int c    = lane & 15;
    const int row0 = blockIdx.x * 4;

    // ---- zero activation buffers once (rows 4..15 and pad cols stay zero forever) ----
    for (int i = tid; i < 16 * (XS / 2); i += 256) {
        ((int*)sSI)[i] = 0; ((int*)sH1)[i] = 0; ((int*)sH2)[i] = 0;
    }
    sY[w * 64 + lane] = y0[(size_t)(row0 + w) * 64 + lane];

    // ---- weights -> bf16 B-fragments in registers (uniform path, constant indices) ----
    // B-frag for tile n0: lane holds B[k=q*8+j][n=n0+c] = Wrow[n0+c][k]
    short8 wL1[2][3], wL2[2][4], wL3[4];
    float  bL1[2], bL2[2], bL3;
    #pragma unroll
    for (int t = 0; t < 2; ++t) {
        const int n = 32 * w + t * 16 + c;
        #pragma unroll
        for (int ks = 0; ks < 3; ++ks) {
            const int k0 = ks * 32 + q * 8;
            short8 v;
            #pragma unroll
            for (int j = 0; j < 8; ++j) {
                const int k = k0 + j;
                const float f = (k < 65) ? gw0[n * 65 + k] : 0.f;
                v[j] = (short)f2bf(f);
            }
            wL1[t][ks] = v;
        }
        #pragma unroll
        for (int ks = 0; ks < 4; ++ks) {
            const int k0 = ks * 32 + q * 8;
            short8 v;
            #pragma unroll
            for (int j = 0; j < 8; ++j) v[j] = (short)f2bf(gw1[n * 128 + k0 + j]);
            wL2[t][ks] = v;
        }
        bL1[t] = gb0[n]; bL2[t] = gb1[n];
    }
    {
        const int n = 16 * w + c;
        #pragma unroll
        for (int ks = 0; ks < 4; ++ks) {
            const int k0 = ks * 32 + q * 8;
            short8 v;
            #pragma unroll
            for (int j = 0; j < 8; ++j) v[j] = (short)f2bf(gw2[n * 128 + k0 + j]);
            wL3[ks] = v;
        }
        bL3 = gb2[n];
    }

    const float dtv = ts[1] - ts[0];
    const float ts0 = ts[0];

    __syncthreads();

    #pragma unroll 1
    for (int step = 0; step < NSTEPS; ++step) {
        const float tstep = ts0 + (float)step * dtv;  // == ts[step] bit-exactly

        #pragma unroll 1
        for (int s = 0; s < 6; ++s) {
            // ---- build stage input (fp32 math, bf16 store); thread (w, lane) owns (row w, dim lane)
            {
                float acc = 0.f;
                for (int qq = 0; qq < s; ++qq) acc += dA[s][qq] * sK[qq * 256 + w * 64 + lane];
                const float si = sY[w * 64 + lane] + dtv * acc;
                sSI[w * XS + 1 + lane] = f2bf(si);
                if (lane == 0) sSI[w * XS] = f2bf(tstep + dC6[s] * dtv);
            }
            __syncthreads();

            // ---- L1: SI[K=96] -> H1, relu ----
            {
                f32x4 a0 = {0.f, 0.f, 0.f, 0.f}, a1 = {0.f, 0.f, 0.f, 0.f};
                #pragma unroll
                for (int ks = 0; ks < 3; ++ks) {
                    short8 x = *(const short8*)(&sSI[c * XS + ks * 32 + q * 8]);
                    a0 = __builtin_amdgcn_mfma_f32_16x16x32_bf16(x, wL1[0][ks], a0, 0, 0, 0);
                    a1 = __builtin_amdgcn_mfma_f32_16x16x32_bf16(x, wL1[1][ks], a1, 0, 0, 0);
                }
                if (lane < 16) {
                    #pragma unroll
                    for (int r = 0; r < 4; ++r) {
                        sH1[r * XS + 32 * w + c]      = f2bf(fmaxf(a0[r] + bL1[0], 0.f));
                        sH1[r * XS + 32 * w + 16 + c] = f2bf(fmaxf(a1[r] + bL1[1], 0.f));
                    }
                }
            }
            __syncthreads();

            // ---- L2: H1[K=128] -> H2, relu ----
            {
                f32x4 a0 = {0.f, 0.f, 0.f, 0.f}, a1 = {0.f, 0.f, 0.f, 0.f};
                #pragma unroll
                for (int ks = 0; ks < 4; ++ks) {
                    short8 x = *(const short8*)(&sH1[c * XS + ks * 32 + q * 8]);
                    a0 = __builtin_amdgcn_mfma_f32_16x16x32_bf16(x, wL2[0][ks], a0, 0, 0, 0);
                    a1 = __builtin_amdgcn_mfma_f32_16x16x32_bf16(x, wL2[1][ks], a1, 0, 0, 0);
                }
                if (lane < 16) {
                    #pragma unroll
                    for (int r = 0; r < 4; ++r) {
                        sH2[r * XS + 32 * w + c]      = f2bf(fmaxf(a0[r] + bL2[0], 0.f));
                        sH2[r * XS + 32 * w + 16 + c] = f2bf(fmaxf(a1[r] + bL2[1], 0.f));
                    }
                }
            }
            __syncthreads();

            // ---- L3: H2[K=128] -> k_s (fp32, no relu) ----
            {
                f32x4 a0 = {0.f, 0.f, 0.f, 0.f};
                #pragma unroll
                for (int ks = 0; ks < 4; ++ks) {
                    short8 x = *(const short8*)(&sH2[c * XS + ks * 32 + q * 8]);
                    a0 = __builtin_amdgcn_mfma_f32_16x16x32_bf16(x, wL3[ks], a0, 0, 0, 0);
                }
                if (lane < 16) {
                    #pragma unroll
                    for (int r = 0; r < 4; ++r)
                        sK[s * 256 + r * 64 + 16 * w + c] = a0[r] + bL3;
                }
            }
            __syncthreads();
        }

        // ---- y update (fp32; same-thread mapping as build) ----
        {
            float acc = 0.f;
            #pragma unroll
            for (int qq = 0; qq < 6; ++qq) acc += dB6[qq] * sK[qq * 256 + w * 64 + lane];
            sY[w * 64 + lane] += dtv * acc;
        }
    }

    out[(size_t)(row0 + w) * 64 + lane] = sY[w * 64 + lane];
}

extern "C" void kernel_launch(void* const* d_in, const int* in_sizes, int n_in,
                              void* d_out, int out_size, void* d_ws, size_t ws_size,
                              hipStream_t stream) {
    const float* y0 = (const float*)d_in[0];
    const float* ts = (const float*)d_in[1];
    const float* w0 = (const float*)d_in[2];
    const float* b0 = (const float*)d_in[3];
    const float* w1 = (const float*)d_in[4];
    const float* b1 = (const float*)d_in[5];
    const float* w2 = (const float*)d_in[6];
    const float* b2 = (const float*)d_in[7];
    float* out = (float*)d_out;

    node_solve<<<dim3(512), dim3(256), 0, stream>>>(y0, ts, w0, b0, w1, b1, w2, b2, out);
}

// Round 5
// 345.473 us; speedup vs baseline: 5.8357x; 1.0645x over previous
//
#include <hip/hip_runtime.h>

typedef __attribute__((ext_vector_type(8))) short short8;
typedef __attribute__((ext_vector_type(4))) float f32x4;

// dA2[sn][q] = coefficient of k_q in stage sn's input (zero-padded; row 0 unused)
__device__ __constant__ float dA2[6][6] = {
  {0.f, 0.f, 0.f, 0.f, 0.f, 0.f},
  {0.161f, 0.f, 0.f, 0.f, 0.f, 0.f},
  {-0.008480655492356989f, 0.335480655492357f, 0.f, 0.f, 0.f, 0.f},
  {2.8971530571054935f, -6.359448489975075f, 4.3622954328695815f, 0.f, 0.f, 0.f},
  {5.325864828439257f, -11.748883564062828f, 7.4955393428898365f, -0.09249506636175525f, 0.f, 0.f},
  {5.86145544294642f, -12.92096931784711f, 8.159367898576159f, -0.071584973281401f, -0.028269050394068383f, 0.f}
};
__device__ __constant__ float dC6[6] = {0.f, 0.161f, 0.327f, 0.9f, 0.9800255409045097f, 1.0f};
__device__ __constant__ float dB6v[6] = {0.09646076681806523f, 0.01f, 0.4798896504144996f,
                                         1.379008574103742f, -3.290069515436081f, 2.324710524099774f};

#define NSTEPS 49
#define XS 136   // bf16 activation row stride (272 B): 16B-aligned A-frag reads, 2-way conflicts max

__device__ __forceinline__ unsigned short f2bf(float f) {
    unsigned u = __builtin_bit_cast(unsigned, f);
    u += 0x7fff + ((u >> 16) & 1);
    return (unsigned short)(u >> 16);
}

// 256 blocks x 512 thr (8 waves), M=8 batch rows/block, 1 block/CU (2 waves/SIMD).
// Wave w: N-tile n0=16w for L1/L2 (8 tiles = 128 cols); waves 0-3 do L3 (64 cols).
// A-frag (shared by all waves): lane(c=lane&15,q=lane>>4) holds A[m=c][k=q*8+j].
// C/D: col=lane&15, row=q*4+reg -> valid rows 0-7 live in lanes<32.
// L3-owner lanes keep k_q and y in REGISTERS; L3 epilogue computes next stage's
// input directly (build phase + sK/sY arrays eliminated -> 3 barriers/stage).
extern "C" __global__ void __launch_bounds__(512, 2)
node_solve(const float* __restrict__ y0, const float* __restrict__ ts,
           const float* __restrict__ gw0, const float* __restrict__ gb0,
           const float* __restrict__ gw1, const float* __restrict__ gb1,
           const float* __restrict__ gw2, const float* __restrict__ gb2,
           float* __restrict__ out)
{
    __shared__ __align__(16) unsigned short sSI[16 * XS];  // [t | y' | zero pad], K-extent 96
    __shared__ __align__(16) unsigned short sH1[16 * XS];  // K=128
    __shared__ __align__(16) unsigned short sH2[16 * XS];  // K=128

    const int tid  = threadIdx.x;
    const int w    = tid >> 6;
    const int lane = tid & 63;
    const int q    = lane >> 4;
    const int c    = lane & 15;
    const int n0   = 16 * w;
    const int row0 = blockIdx.x * 8;

    // ---- zero M-pad rows 8..15 (all bufs) and SI K-pad cols 65..135 (rows 0..7) ----
    for (int i = tid; i < 8 * XS; i += 512) {
        int r = 8 + i / XS, col = i - (r - 8) * XS;
        sSI[r * XS + col] = 0; sH1[r * XS + col] = 0; sH2[r * XS + col] = 0;
    }
    for (int i = tid; i < 8 * 71; i += 512) {
        int r = i / 71, col = 65 + (i - r * 71);
        sSI[r * XS + col] = 0;
    }
    // ---- init SI rows 0..7: y0 (bf16) + time col ----
    sSI[w * XS + 1 + lane] = f2bf(y0[(size_t)(row0 + w) * 64 + lane]);
    if (tid < 8) sSI[tid * XS] = f2bf(ts[0]);

    // ---- weights -> register B-frags: lane holds B[k=ks*32+q*8+j][n0+c] = W[n0+c][k] ----
    short8 wL1[3], wL2[4], wL3[4];
    {
        const int n = n0 + c;
        #pragma unroll
        for (int ks = 0; ks < 3; ++ks) {
            short8 v;
            #pragma unroll
            for (int j = 0; j < 8; ++j) {
                const int k = ks * 32 + q * 8 + j;
                v[j] = (short)f2bf(k < 65 ? gw0[n * 65 + k] : 0.f);
            }
            wL1[ks] = v;
        }
        #pragma unroll
        for (int ks = 0; ks < 4; ++ks) {
            short8 v;
            #pragma unroll
            for (int j = 0; j < 8; ++j) v[j] = (short)f2bf(gw1[n * 128 + ks * 32 + q * 8 + j]);
            wL2[ks] = v;
        }
        if (w < 4) {
            #pragma unroll
            for (int ks = 0; ks < 4; ++ks) {
                short8 v;
                #pragma unroll
                for (int j = 0; j < 8; ++j) v[j] = (short)f2bf(gw2[n * 128 + ks * 32 + q * 8 + j]);
                wL3[ks] = v;
            }
        }
    }
    const float bL1 = gb0[n0 + c];
    const float bL2 = gb1[n0 + c];
    const float bL3 = (w < 4) ? gb2[n0 + c] : 0.f;

    // ---- persistent per-lane state (L3 owner lanes: w<4, q<2): y and k1..k6 ----
    float sy[4] = {0.f, 0.f, 0.f, 0.f};
    float k0[4], k1[4], k2[4], k3[4], k4[4], k5[4];
    #pragma unroll
    for (int r = 0; r < 4; ++r) { k0[r]=0.f; k1[r]=0.f; k2[r]=0.f; k3[r]=0.f; k4[r]=0.f; k5[r]=0.f; }
    if (w < 4 && q < 2) {
        #pragma unroll
        for (int r = 0; r < 4; ++r)
            sy[r] = y0[(size_t)(row0 + q * 4 + r) * 64 + n0 + c];
    }

    const float ts0 = ts[0];
    const float dtv = ts[1] - ts[0];

    __syncthreads();

    #pragma unroll 1
    for (int step = 0; step < NSTEPS; ++step) {
        const float tstep = ts0 + (float)step * dtv;

        #pragma unroll 1
        for (int s = 0; s < 6; ++s) {
            // ---- P1: L1 (SI K=96 -> H1, relu) ----
            {
                const unsigned short* xb = &sSI[c * XS + q * 8];
                short8 x0 = *(const short8*)(xb);
                short8 x1 = *(const short8*)(xb + 32);
                short8 x2 = *(const short8*)(xb + 64);
                f32x4 aa = {0.f,0.f,0.f,0.f}, ab = {0.f,0.f,0.f,0.f};
                aa = __builtin_amdgcn_mfma_f32_16x16x32_bf16(x0, wL1[0], aa, 0, 0, 0);
                ab = __builtin_amdgcn_mfma_f32_16x16x32_bf16(x1, wL1[1], ab, 0, 0, 0);
                aa = __builtin_amdgcn_mfma_f32_16x16x32_bf16(x2, wL1[2], aa, 0, 0, 0);
                aa = aa + ab;
                if (q < 2) {
                    #pragma unroll
                    for (int r = 0; r < 4; ++r)
                        sH1[(q * 4 + r) * XS + n0 + c] = f2bf(fmaxf(aa[r] + bL1, 0.f));
                }
            }
            __syncthreads();

            // ---- P2: L2 (H1 K=128 -> H2, relu) ----
            {
                const unsigned short* xb = &sH1[c * XS + q * 8];
                short8 x0 = *(const short8*)(xb);
                short8 x1 = *(const short8*)(xb + 32);
                short8 x2 = *(const short8*)(xb + 64);
                short8 x3 = *(const short8*)(xb + 96);
                f32x4 aa = {0.f,0.f,0.f,0.f}, ab = {0.f,0.f,0.f,0.f};
                aa = __builtin_amdgcn_mfma_f32_16x16x32_bf16(x0, wL2[0], aa, 0, 0, 0);
                ab = __builtin_amdgcn_mfma_f32_16x16x32_bf16(x1, wL2[1], ab, 0, 0, 0);
                aa = __builtin_amdgcn_mfma_f32_16x16x32_bf16(x2, wL2[2], aa, 0, 0, 0);
                ab = __builtin_amdgcn_mfma_f32_16x16x32_bf16(x3, wL2[3], ab, 0, 0, 0);
                aa = aa + ab;
                if (q < 2) {
                    #pragma unroll
                    for (int r = 0; r < 4; ++r)
                        sH2[(q * 4 + r) * XS + n0 + c] = f2bf(fmaxf(aa[r] + bL2, 0.f));
                }
            }
            __syncthreads();

            // ---- P3: L3 (H2 K=128 -> k_s) + fused build of next stage input ----
            if (w < 4) {
                const unsigned short* xb = &sH2[c * XS + q * 8];
                short8 x0 = *(const short8*)(xb);
                short8 x1 = *(const short8*)(xb + 32);
                short8 x2 = *(const short8*)(xb + 64);
                short8 x3 = *(const short8*)(xb + 96);
                f32x4 aa = {0.f,0.f,0.f,0.f}, ab = {0.f,0.f,0.f,0.f};
                aa = __builtin_amdgcn_mfma_f32_16x16x32_bf16(x0, wL3[0], aa, 0, 0, 0);
                ab = __builtin_amdgcn_mfma_f32_16x16x32_bf16(x1, wL3[1], ab, 0, 0, 0);
                aa = __builtin_amdgcn_mfma_f32_16x16x32_bf16(x2, wL3[2], aa, 0, 0, 0);
                ab = __builtin_amdgcn_mfma_f32_16x16x32_bf16(x3, wL3[3], ab, 0, 0, 0);
                aa = aa + ab;
                if (q < 2) {
                    float kv[4];
                    #pragma unroll
                    for (int r = 0; r < 4; ++r) kv[r] = aa[r] + bL3;
                    // store k_s into named registers (wave-uniform branch on s)
                    if      (s == 0) { k0[0]=kv[0]; k0[1]=kv[1]; k0[2]=kv[2]; k0[3]=kv[3]; }
                    else if (s == 1) { k1[0]=kv[0]; k1[1]=kv[1]; k1[2]=kv[2]; k1[3]=kv[3]; }
                    else if (s == 2) { k2[0]=kv[0]; k2[1]=kv[1]; k2[2]=kv[2]; k2[3]=kv[3]; }
                    else if (s == 3) { k3[0]=kv[0]; k3[1]=kv[1]; k3[2]=kv[2]; k3[3]=kv[3]; }
                    else if (s == 4) { k4[0]=kv[0]; k4[1]=kv[1]; k4[2]=kv[2]; k4[3]=kv[3]; }
                    else             { k5[0]=kv[0]; k5[1]=kv[1]; k5[2]=kv[2]; k5[3]=kv[3]; }

                    float si[4];
                    if (s < 5) {
                        const float a0c = dA2[s + 1][0], a1c = dA2[s + 1][1], a2c = dA2[s + 1][2];
                        const float a3c = dA2[s + 1][3], a4c = dA2[s + 1][4], a5c = dA2[s + 1][5];
                        #pragma unroll
                        for (int r = 0; r < 4; ++r)
                            si[r] = sy[r] + dtv * (a0c*k0[r] + a1c*k1[r] + a2c*k2[r]
                                                 + a3c*k3[r] + a4c*k4[r] + a5c*k5[r]);
                    } else {
                        #pragma unroll
                        for (int r = 0; r < 4; ++r) {
                            sy[r] += dtv * (dB6v[0]*k0[r] + dB6v[1]*k1[r] + dB6v[2]*k2[r]
                                          + dB6v[3]*k3[r] + dB6v[4]*k4[r] + dB6v[5]*k5[r]);
                            si[r] = sy[r];
                        }
                    }
                    #pragma unroll
                    for (int r = 0; r < 4; ++r)
                        sSI[(q * 4 + r) * XS + 1 + n0 + c] = f2bf(si[r]);
                    // time column for next stage (lanes 0 and 16 of wave 0 cover rows 0..7)
                    if (w == 0 && c == 0) {
                        const float tn = (s < 5) ? (tstep + dC6[s + 1] * dtv) : (tstep + dtv);
                        const unsigned short tb = f2bf(tn);
                        #pragma unroll
                        for (int r = 0; r < 4; ++r) sSI[(q * 4 + r) * XS] = tb;
                    }
                }
            }
            __syncthreads();
        }
    }

    // ---- output: y lives in L3-owner registers ----
    if (w < 4 && q < 2) {
        #pragma unroll
        for (int r = 0; r < 4; ++r)
            out[(size_t)(row0 + q * 4 + r) * 64 + n0 + c] = sy[r];
    }
}

extern "C" void kernel_launch(void* const* d_in, const int* in_sizes, int n_in,
                              void* d_out, int out_size, void* d_ws, size_t ws_size,
                              hipStream_t stream) {
    const float* y0 = (const float*)d_in[0];
    const float* ts = (const float*)d_in[1];
    const float* w0 = (const float*)d_in[2];
    const float* b0 = (const float*)d_in[3];
    const float* w1 = (const float*)d_in[4];
    const float* b1 = (const float*)d_in[5];
    const float* w2 = (const float*)d_in[6];
    const float* b2 = (const float*)d_in[7];
    float* out = (float*)d_out;

    node_solve<<<dim3(256), dim3(512), 0, stream>>>(y0, ts, w0, b0, w1, b1, w2, b2, out);
}

// Round 6
// 325.051 us; speedup vs baseline: 6.2024x; 1.0628x over previous
//
#include <hip/hip_runtime.h>

typedef __attribute__((ext_vector_type(8))) short short8;
typedef __attribute__((ext_vector_type(4))) float f32x4;
typedef __attribute__((ext_vector_type(4))) unsigned short ushort4v;

// dA2[sn][q] = coefficient of k_q in stage sn's input (zero-padded; row 0 unused)
__device__ __constant__ float dA2[6][6] = {
  {0.f, 0.f, 0.f, 0.f, 0.f, 0.f},
  {0.161f, 0.f, 0.f, 0.f, 0.f, 0.f},
  {-0.008480655492356989f, 0.335480655492357f, 0.f, 0.f, 0.f, 0.f},
  {2.8971530571054935f, -6.359448489975075f, 4.3622954328695815f, 0.f, 0.f, 0.f},
  {5.325864828439257f, -11.748883564062828f, 7.4955393428898365f, -0.09249506636175525f, 0.f, 0.f},
  {5.86145544294642f, -12.92096931784711f, 8.159367898576159f, -0.071584973281401f, -0.028269050394068383f, 0.f}
};
__device__ __constant__ float dC6[6] = {0.f, 0.161f, 0.327f, 0.9f, 0.9800255409045097f, 1.0f};
__device__ __constant__ float dB6v[6] = {0.09646076681806523f, 0.01f, 0.4798896504144996f,
                                         1.379008574103742f, -3.290069515436081f, 2.324710524099774f};

#define NSTEPS 49
#define XS 136   // bf16 activation row stride (272 B = 17*16): aligned b128 reads, uniform bank spread

__device__ __forceinline__ unsigned short f2bf(float f) {
    unsigned u = __builtin_bit_cast(unsigned, f);
    u += 0x7fff + ((u >> 16) & 1);
    return (unsigned short)(u >> 16);
}

// 256 blocks x 512 thr (8 waves), M=8 batch rows/block, 1 block/CU.
// TRANSPOSED MFMA: C'[n][m] = sum_k W[n][k] * X[m][k]  (A = weights in registers,
// B = activations; B-frag lane(c=lane&15,q=lane>>4) reads X[row c][k=q*8+j] — contiguous b128).
// C' lane holds n = tile_n0 + q*4+r, m = c  ->  4 consecutive output neurons of batch row c
// = ONE ds_write_b64 (epilogue was 4x ds_write_b16 in the old orientation).
// Input layout permuted to [y0..y63, t, pad..] so L3's fused SI write stays 8B-aligned;
// weight k-index permuted to match. Batch cols m=8..15 are garbage but stay confined
// (m is element-wise through all layers); only SI k-pad cols need one-time zeroing.
extern "C" __global__ void __launch_bounds__(512, 2)
node_solve(const float* __restrict__ y0, const float* __restrict__ ts,
           const float* __restrict__ gw0, const float* __restrict__ gb0,
           const float* __restrict__ gw1, const float* __restrict__ gb1,
           const float* __restrict__ gw2, const float* __restrict__ gb2,
           float* __restrict__ out)
{
    __shared__ __align__(16) unsigned short sSI[16 * XS];  // [y' | t | zero pad], K-extent 96
    __shared__ __align__(16) unsigned short sH1[16 * XS];  // K=128
    __shared__ __align__(16) unsigned short sH2[16 * XS];  // K=128

    const int tid  = threadIdx.x;
    const int w    = tid >> 6;
    const int lane = tid & 63;
    const int q    = lane >> 4;
    const int c    = lane & 15;
    const int n0   = 16 * w;
    const int row0 = blockIdx.x * 8;

    // ---- zero SI cols 0..95 for all 16 rows (k-pad must be 0: zero-weight * NaN = NaN) ----
    for (int i = tid; i < 16 * 48; i += 512) {
        int r = i / 48, j = i - r * 48;
        ((int*)sSI)[r * 68 + j] = 0;
    }
    __syncthreads();
    // ---- init SI: rows 0..7 <- y0 (cols 0..63), time at col 64 (all 16 rows) ----
    {
        int r = tid >> 6, d = tid & 63;
        sSI[r * XS + d] = f2bf(y0[(size_t)(row0 + r) * 64 + d]);
        if (tid < 16) sSI[tid * XS + 64] = f2bf(ts[0]);
    }

    // ---- weights -> register A-frags: lane holds W[n0+c][k = ks*32 + q*8 + j] ----
    // L1 k-permutation: k<64 -> y_k (gw0 col 1+k); k==64 -> t (gw0 col 0); k>64 -> 0
    short8 wL1[3], wL2[4], wL3[4];
    {
        const int n = n0 + c;
        #pragma unroll
        for (int ks = 0; ks < 3; ++ks) {
            short8 v;
            #pragma unroll
            for (int j = 0; j < 8; ++j) {
                const int k = ks * 32 + q * 8 + j;
                float f = (k < 64) ? gw0[n * 65 + 1 + k] : (k == 64 ? gw0[n * 65] : 0.f);
                v[j] = (short)f2bf(f);
            }
            wL1[ks] = v;
        }
        #pragma unroll
        for (int ks = 0; ks < 4; ++ks) {
            short8 v;
            #pragma unroll
            for (int j = 0; j < 8; ++j) v[j] = (short)f2bf(gw1[n * 128 + ks * 32 + q * 8 + j]);
            wL2[ks] = v;
        }
        if (w < 4) {
            #pragma unroll
            for (int ks = 0; ks < 4; ++ks) {
                short8 v;
                #pragma unroll
                for (int j = 0; j < 8; ++j) v[j] = (short)f2bf(gw2[n * 128 + ks * 32 + q * 8 + j]);
                wL3[ks] = v;
            }
        }
    }
    const float bL1 = gb0[n0 + c];
    const float bL2 = gb1[n0 + c];
    const float bL3 = (w < 4) ? gb2[n0 + c] : 0.f;

    // ---- persistent per-lane ODE state (L3 owners w<4): batch row c, dims n0+q*4+r ----
    float sy[4] = {0.f, 0.f, 0.f, 0.f};
    float k0[4], k1[4], k2[4], k3[4], k4[4], k5[4];
    #pragma unroll
    for (int r = 0; r < 4; ++r) { k0[r]=0.f; k1[r]=0.f; k2[r]=0.f; k3[r]=0.f; k4[r]=0.f; k5[r]=0.f; }
    if (w < 4 && c < 8) {
        #pragma unroll
        for (int r = 0; r < 4; ++r)
            sy[r] = y0[(size_t)(row0 + c) * 64 + n0 + q * 4 + r];
    }

    const float ts0 = ts[0];
    const float dtv = ts[1] - ts[0];

    __syncthreads();

    #pragma unroll 1
    for (int step = 0; step < NSTEPS; ++step) {
        const float tstep = ts0 + (float)step * dtv;

        #pragma unroll 1
        for (int s = 0; s < 6; ++s) {
            // ---- P1: L1 (SI K=96 -> H1, relu) ----
            {
                const unsigned short* xb = &sSI[c * XS + q * 8];
                short8 x0 = *(const short8*)(xb);
                short8 x1 = *(const short8*)(xb + 32);
                short8 x2 = *(const short8*)(xb + 64);
                f32x4 aa = {0.f,0.f,0.f,0.f}, ab = {0.f,0.f,0.f,0.f};
                aa = __builtin_amdgcn_mfma_f32_16x16x32_bf16(wL1[0], x0, aa, 0, 0, 0);
                ab = __builtin_amdgcn_mfma_f32_16x16x32_bf16(wL1[1], x1, ab, 0, 0, 0);
                aa = __builtin_amdgcn_mfma_f32_16x16x32_bf16(wL1[2], x2, aa, 0, 0, 0);
                aa = aa + ab;
                ushort4v ov;
                #pragma unroll
                for (int r = 0; r < 4; ++r) ov[r] = f2bf(fmaxf(aa[r] + bL1, 0.f));
                *(ushort4v*)(&sH1[c * XS + n0 + q * 4]) = ov;
            }
            __syncthreads();

            // ---- P2: L2 (H1 K=128 -> H2, relu) ----
            {
                const unsigned short* xb = &sH1[c * XS + q * 8];
                short8 x0 = *(const short8*)(xb);
                short8 x1 = *(const short8*)(xb + 32);
                short8 x2 = *(const short8*)(xb + 64);
                short8 x3 = *(const short8*)(xb + 96);
                f32x4 aa = {0.f,0.f,0.f,0.f}, ab = {0.f,0.f,0.f,0.f};
                aa = __builtin_amdgcn_mfma_f32_16x16x32_bf16(wL2[0], x0, aa, 0, 0, 0);
                ab = __builtin_amdgcn_mfma_f32_16x16x32_bf16(wL2[1], x1, ab, 0, 0, 0);
                aa = __builtin_amdgcn_mfma_f32_16x16x32_bf16(wL2[2], x2, aa, 0, 0, 0);
                ab = __builtin_amdgcn_mfma_f32_16x16x32_bf16(wL2[3], x3, ab, 0, 0, 0);
                aa = aa + ab;
                ushort4v ov;
                #pragma unroll
                for (int r = 0; r < 4; ++r) ov[r] = f2bf(fmaxf(aa[r] + bL2, 0.f));
                *(ushort4v*)(&sH2[c * XS + n0 + q * 4]) = ov;
            }
            __syncthreads();

            // ---- P3: L3 (H2 K=128 -> k_s) + fused state update + next-stage SI build ----
            if (w < 4) {
                const unsigned short* xb = &sH2[c * XS + q * 8];
                short8 x0 = *(const short8*)(xb);
                short8 x1 = *(const short8*)(xb + 32);
                short8 x2 = *(const short8*)(xb + 64);
                short8 x3 = *(const short8*)(xb + 96);
                f32x4 aa = {0.f,0.f,0.f,0.f}, ab = {0.f,0.f,0.f,0.f};
                aa = __builtin_amdgcn_mfma_f32_16x16x32_bf16(wL3[0], x0, aa, 0, 0, 0);
                ab = __builtin_amdgcn_mfma_f32_16x16x32_bf16(wL3[1], x1, ab, 0, 0, 0);
                aa = __builtin_amdgcn_mfma_f32_16x16x32_bf16(wL3[2], x2, aa, 0, 0, 0);
                ab = __builtin_amdgcn_mfma_f32_16x16x32_bf16(wL3[3], x3, ab, 0, 0, 0);
                aa = aa + ab;

                float kv[4];
                #pragma unroll
                for (int r = 0; r < 4; ++r) kv[r] = aa[r] + bL3;
                if      (s == 0) { k0[0]=kv[0]; k0[1]=kv[1]; k0[2]=kv[2]; k0[3]=kv[3]; }
                else if (s == 1) { k1[0]=kv[0]; k1[1]=kv[1]; k1[2]=kv[2]; k1[3]=kv[3]; }
                else if (s == 2) { k2[0]=kv[0]; k2[1]=kv[1]; k2[2]=kv[2]; k2[3]=kv[3]; }
                else if (s == 3) { k3[0]=kv[0]; k3[1]=kv[1]; k3[2]=kv[2]; k3[3]=kv[3]; }
                else if (s == 4) { k4[0]=kv[0]; k4[1]=kv[1]; k4[2]=kv[2]; k4[3]=kv[3]; }
                else             { k5[0]=kv[0]; k5[1]=kv[1]; k5[2]=kv[2]; k5[3]=kv[3]; }

                float si[4];
                if (s < 5) {
                    const float a0c = dA2[s + 1][0], a1c = dA2[s + 1][1], a2c = dA2[s + 1][2];
                    const float a3c = dA2[s + 1][3], a4c = dA2[s + 1][4], a5c = dA2[s + 1][5];
                    #pragma unroll
                    for (int r = 0; r < 4; ++r)
                        si[r] = sy[r] + dtv * (a0c*k0[r] + a1c*k1[r] + a2c*k2[r]
                                             + a3c*k3[r] + a4c*k4[r] + a5c*k5[r]);
                } else {
                    #pragma unroll
                    for (int r = 0; r < 4; ++r) {
                        sy[r] += dtv * (dB6v[0]*k0[r] + dB6v[1]*k1[r] + dB6v[2]*k2[r]
                                      + dB6v[3]*k3[r] + dB6v[4]*k4[r] + dB6v[5]*k5[r]);
                        si[r] = sy[r];
                    }
                }
                ushort4v ov;
                #pragma unroll
                for (int r = 0; r < 4; ++r) ov[r] = f2bf(si[r]);
                *(ushort4v*)(&sSI[c * XS + n0 + q * 4]) = ov;
                if (w == 0 && q == 0) {
                    const float tn = (s < 5) ? (tstep + dC6[s + 1] * dtv) : (tstep + dtv);
                    sSI[c * XS + 64] = f2bf(tn);
                }
            }
            __syncthreads();
        }
    }

    // ---- output: y lives in L3-owner registers; real batch rows are c<8 ----
    if (w < 4 && c < 8) {
        float4 v = make_float4(sy[0], sy[1], sy[2], sy[3]);
        *(float4*)(&out[(size_t)(row0 + c) * 64 + n0 + q * 4]) = v;
    }
}

extern "C" void kernel_launch(void* const* d_in, const int* in_sizes, int n_in,
                              void* d_out, int out_size, void* d_ws, size_t ws_size,
                              hipStream_t stream) {
    const float* y0 = (const float*)d_in[0];
    const float* ts = (const float*)d_in[1];
    const float* w0 = (const float*)d_in[2];
    const float* b0 = (const float*)d_in[3];
    const float* w1 = (const float*)d_in[4];
    const float* b1 = (const float*)d_in[5];
    const float* w2 = (const float*)d_in[6];
    const float* b2 = (const float*)d_in[7];
    float* out = (float*)d_out;

    node_solve<<<dim3(256), dim3(512), 0, stream>>>(y0, ts, w0, b0, w1, b1, w2, b2, out);
}